// Round 4
// baseline (284.816 us; speedup 1.0000x reference)
//
#include <hip/hip_runtime.h>
#include <hip/hip_bf16.h>
#include <math.h>

typedef __attribute__((ext_vector_type(8))) short short8;
typedef __attribute__((ext_vector_type(4))) float f32x4;

#define NB 8192
#define ND 256
#define NT 32             // 256-row tiles per side
#define TILE_USH 16384    // one 64-row K-major tile in ushorts
#define NBLK 528          // 32*33/2 triangle tiles
#define LN2f 0.6931471805599453f

__device__ __forceinline__ float bf2f(ushort u) {
  unsigned int x = ((unsigned int)u) << 16;
  return __builtin_bit_cast(float, x);
}
__device__ __forceinline__ ushort f2bf(float x) {
  return __builtin_bit_cast(ushort, __float2bfloat16(x));
}

// ---- prep: normalize, fold 1/sqrt(T*ln2), quantize, exact ||q||^2, and ----
// ---- transpose to K-major tiles hsK[tile][unit 0..31][row 0..63][8] -------
__global__ void prep_kernel(const float* __restrict__ h, ushort* __restrict__ hsK,
                            float* __restrict__ dbuf) {
  __shared__ ushort T[64 * 256];   // 32 KB, 16B-unit swizzled: slot = u ^ (r&31)
  const float SCALE = 1.0f / sqrtf(0.07f * 0.6931471805599453f);
  int tid = threadIdx.x, lane = tid & 63, wave = tid >> 6;
  int r0 = blockIdx.x * 64;

#pragma unroll 4
  for (int i = 0; i < 16; ++i) {
    int r = wave * 16 + i;
    const float4* rp = reinterpret_cast<const float4*>(h + (size_t)(r0 + r) * ND);
    float4 v = rp[lane];
    float ss = v.x * v.x + v.y * v.y + v.z * v.z + v.w * v.w;
#pragma unroll
    for (int d = 1; d <= 32; d <<= 1) ss += __shfl_xor(ss, d);
    float scale = SCALE / fmaxf(sqrtf(ss), 1e-12f);
    ushort4 o;
    o.x = f2bf(v.x * scale);
    o.y = f2bf(v.y * scale);
    o.z = f2bf(v.z * scale);
    o.w = f2bf(v.w * scale);
    int slot = (lane >> 1) ^ (r & 31);
    *reinterpret_cast<ushort4*>(
        reinterpret_cast<char*>(T) + r * 512 + slot * 16 + (lane & 1) * 8) = o;
    float qx = bf2f(o.x), qy = bf2f(o.y), qz = bf2f(o.z), qw = bf2f(o.w);
    float dd = qx * qx + qy * qy + qz * qz + qw * qw;
#pragma unroll
    for (int d = 1; d <= 32; d <<= 1) dd += __shfl_xor(dd, d);
    if (lane == 0) dbuf[r0 + r] = dd;
  }
  __syncthreads();
  ushort* dst = hsK + (size_t)blockIdx.x * TILE_USH;
#pragma unroll
  for (int k = 0; k < 8; ++k) {
    int S = k * 256 + tid;          // 16B chunk index: S = u*64 + r
    int r = S & 63, u = S >> 6;
    int slot = u ^ (r & 31);
    *reinterpret_cast<short8*>(dst + S * 8) = *reinterpret_cast<const short8*>(
        reinterpret_cast<const char*>(T) + r * 512 + slot * 16);
  }
}

// ---- per-class sums (deterministic stride-scan) + member counts -----------
__global__ __launch_bounds__(1024)
void classsum_kernel(const ushort* __restrict__ hsK, const int* __restrict__ labels,
                     float* __restrict__ Cs, float* __restrict__ cnt) {
  __shared__ int L[NB];            // 32 KB
  __shared__ float red[4][256];    // 4 KB
  __shared__ int lcnt;
  int c = blockIdx.x, t = threadIdx.x;
  if (t == 0) lcnt = 0;
  for (int i = t; i < NB; i += 1024) L[i] = labels[i];
  __syncthreads();
  int grp = t >> 8, col = t & 255;
  float acc = 0.f;
  int myn = 0;
  for (int i = grp; i < NB; i += 4) {
    if (L[i] == c) {
      acc += bf2f(hsK[(size_t)(i >> 6) * TILE_USH + (col >> 3) * 512 +
                      (i & 63) * 8 + (col & 7)]);
      ++myn;
    }
  }
  red[grp][col] = acc;
  if (col == 0) atomicAdd(&lcnt, myn);   // integer: order-independent
  __syncthreads();
  if (grp == 0) {
    Cs[c * ND + col] = red[0][col] + red[1][col] + red[2][col] + red[3][col];
    if (col == 0) cnt[c] = (float)lcnt;
  }
}

// stage one 64-col K-major tile (32KB) into LDS: pure linear copy
__device__ __forceinline__ void stageB(ushort* lds, const ushort* gsrc,
                                       int wave, int lane) {
#pragma unroll
  for (int c = 0; c < 8; ++c) {
    int base = (wave * 8 + c) * 512;
    __builtin_amdgcn_global_load_lds(
        (const __attribute__((address_space(1))) unsigned int*)(gsrc + base + lane * 8),
        (__attribute__((address_space(3))) unsigned int*)(lds + base),
        16, 0, 0);
  }
}

// ---- main: triangle tiles; exp2 sums into row- and col-accumulators -------
__global__ __launch_bounds__(256, 2)
void main_kernel(const ushort* __restrict__ hsK,
                 float* __restrict__ rowpart, float* __restrict__ colpart) {
  __shared__ ushort Blds[2][64 * 256];   // 64 KB
  int tid = threadIdx.x, lane = tid & 63, wave = tid >> 6;
  int g = lane >> 4, cl = lane & 15;

  int nid = (blockIdx.x & 7) * 66 + (blockIdx.x >> 3);   // 528 = 8*66, bijective
  int rb = 0, t2 = nid;
  while (t2 >= NT - rb) { t2 -= NT - rb; ++rb; }
  int cb = rb + t2;
  bool diag = (rb == cb);

  const ushort* At = hsK + (size_t)(rb * 4 + wave) * TILE_USH;
  short8 af[4][8];
#pragma unroll
  for (int rf = 0; rf < 4; ++rf)
#pragma unroll
    for (int kk = 0; kk < 8; ++kk)
      af[rf][kk] = *reinterpret_cast<const short8*>(
          At + ((kk * 4 + g) * 64 + rf * 16 + cl) * 8);

  float s[16], ccum[16];
#pragma unroll
  for (int i = 0; i < 16; ++i) { s[i] = 0.f; ccum[i] = 0.f; }

  const ushort* Bbase = hsK + (size_t)(cb * 4) * TILE_USH;
  stageB(Blds[0], Bbase, wave, lane);
  __syncthreads();

  for (int it = 0; it < 4; ++it) {
    if (it + 1 < 4)
      stageB(Blds[(it + 1) & 1], Bbase + (size_t)(it + 1) * TILE_USH, wave, lane);
    const ushort* Bt = Blds[it & 1];

#pragma unroll
    for (int cf = 0; cf < 4; ++cf) {
      short8 bfr[8];
#pragma unroll
      for (int kk = 0; kk < 8; ++kk)
        bfr[kk] = *reinterpret_cast<const short8*>(
            Bt + ((kk * 4 + g) * 64 + cf * 16 + cl) * 8);
      f32x4 acc[4];
#pragma unroll
      for (int rf = 0; rf < 4; ++rf) acc[rf] = (f32x4){0.f, 0.f, 0.f, 0.f};
#pragma unroll
      for (int kk = 0; kk < 8; ++kk) {
#pragma unroll
        for (int rf = 0; rf < 4; ++rf)
          acc[rf] = __builtin_amdgcn_mfma_f32_16x16x32_bf16(af[rf][kk], bfr[kk],
                                                            acc[rf], 0, 0, 0);
      }
      float csum = 0.f;
#pragma unroll
      for (int rf = 0; rf < 4; ++rf)
#pragma unroll
        for (int q = 0; q < 4; ++q) {
          float e = __builtin_amdgcn_exp2f(acc[rf][q]);
          s[rf * 4 + q] += e;
          csum += e;
        }
      ccum[it * 4 + cf] = csum;
    }
    __syncthreads();   // drains prefetch vmcnt + protects Blds
  }

  // row partials: reduce over cl (this lane's 16-col subsets)
#pragma unroll
  for (int i = 0; i < 16; ++i) {
#pragma unroll
    for (int d = 1; d <= 8; d <<= 1) s[i] += __shfl_xor(s[i], d);
  }
  if (cl == 0) {
    int R0 = rb * 256 + wave * 64;
#pragma unroll
    for (int rf = 0; rf < 4; ++rf)
#pragma unroll
      for (int q = 0; q < 4; ++q)
        rowpart[(size_t)cb * NB + R0 + rf * 16 + g * 4 + q] = s[rf * 4 + q];
  }

  if (!diag) {
    // col partials: reduce over row-groups g (lane bits 4,5), then over waves
#pragma unroll
    for (int k = 0; k < 16; ++k) {
      ccum[k] += __shfl_xor(ccum[k], 16);
      ccum[k] += __shfl_xor(ccum[k], 32);
    }
    float* cr = reinterpret_cast<float*>(&Blds[0][0]);   // safe: Blds[0] dead
    if (g == 0) {
#pragma unroll
      for (int k = 0; k < 16; ++k) cr[(wave * 16 + k) * 16 + cl] = ccum[k];
    }
    __syncthreads();
    int k = tid >> 4, c2 = tid & 15;
    float v = cr[(0 * 16 + k) * 16 + c2] + cr[(1 * 16 + k) * 16 + c2] +
              cr[(2 * 16 + k) * 16 + c2] + cr[(3 * 16 + k) * 16 + c2];
    int col = cb * 256 + (k >> 2) * 64 + (k & 3) * 16 + c2;
    colpart[(size_t)rb * NB + col] = v;
  }
}

// ---- per-row loss ----------------------------------------------------------
__global__ void rowloss_kernel(const ushort* __restrict__ hsK,
                               const int* __restrict__ labels,
                               const float* __restrict__ Cs,
                               const float* __restrict__ cnt,
                               const float* __restrict__ rowpart,
                               const float* __restrict__ colpart,
                               const float* __restrict__ dbuf,
                               float2* __restrict__ rl) {
  int lane = threadIdx.x & 63, wave = threadIdx.x >> 6;
  int row = blockIdx.x * 4 + wave;
  int lbl = labels[row];
  const ushort* tp = hsK + (size_t)(row >> 6) * TILE_USH + (size_t)(row & 63) * 8;
  ushort4 qb = *reinterpret_cast<const ushort4*>(tp + (lane >> 1) * 512 + (lane & 1) * 4);
  float4 cv = reinterpret_cast<const float4*>(Cs + (size_t)lbl * ND)[lane];
  float dot = bf2f(qb.x) * cv.x + bf2f(qb.y) * cv.y +
              bf2f(qb.z) * cv.z + bf2f(qb.w) * cv.w;
#pragma unroll
  for (int d = 1; d <= 32; d <<= 1) dot += __shfl_xor(dot, d);

  int rb0 = row >> 8;
  float part = 0.f;
  if (lane < 32) {
    const float* base = (lane >= rb0) ? rowpart : colpart;
    part = base[(size_t)lane * NB + row];
  }
#pragma unroll
  for (int d = 1; d <= 16; d <<= 1) part += __shfl_xor(part, d);

  if (lane == 0) {
    float dself = dbuf[row];
    float sfull = part;
    float s = sfull - (1.0f - 1e-8f) * __builtin_amdgcn_exp2f(dself);
    float denom2 = log2f(s);
    float Sp2 = dot - dself;
    float n = cnt[lbl] - 1.0f;
    float li = 0.f, val = 0.f;
    if (n > 0.5f) { li = -LN2f * (Sp2 - n * denom2) / n; val = 1.f; }
    rl[row] = make_float2(li, val);
  }
}

__global__ void reduce_kernel(const float2* __restrict__ rl, float* __restrict__ out) {
  int t = threadIdx.x;
  float L = 0.f, V = 0.f;
  for (int r = t; r < NB; r += 256) { float2 p = rl[r]; L += p.x; V += p.y; }
#pragma unroll
  for (int d = 1; d <= 32; d <<= 1) { L += __shfl_xor(L, d); V += __shfl_xor(V, d); }
  __shared__ float sL[4], sV[4];
  if ((t & 63) == 0) { sL[t >> 6] = L; sV[t >> 6] = V; }
  __syncthreads();
  if (t == 0)
    out[0] = (sL[0] + sL[1] + sL[2] + sL[3]) /
             fmaxf(sV[0] + sV[1] + sV[2] + sV[3], 1.f);
}

extern "C" void kernel_launch(void* const* d_in, const int* in_sizes, int n_in,
                              void* d_out, int out_size, void* d_ws, size_t ws_size,
                              hipStream_t stream) {
  const float* hidden = (const float*)d_in[0];
  const int* labels = (const int*)d_in[1];
  float* out = (float*)d_out;

  ushort* hsK     = (ushort*)d_ws;                        // 4 MB
  float* dbuf     = (float*)((char*)d_ws + 4194304);      // 32 KB
  float* Cs       = (float*)((char*)d_ws + 4227072);      // 100 KB
  float* cnt      = (float*)((char*)d_ws + 4329472);      // 0.5 KB
  float* rowpart  = (float*)((char*)d_ws + 4330496);      // 1 MB
  float* colpart  = (float*)((char*)d_ws + 5379072);      // 1 MB
  float2* rl      = (float2*)((char*)d_ws + 6427648);     // 64 KB

  prep_kernel<<<NB / 64, 256, 0, stream>>>(hidden, hsK, dbuf);
  classsum_kernel<<<100, 1024, 0, stream>>>(hsK, labels, Cs, cnt);
  main_kernel<<<NBLK, 256, 0, stream>>>(hsK, rowpart, colpart);
  rowloss_kernel<<<NB / 4, 256, 0, stream>>>(hsK, labels, Cs, cnt, rowpart,
                                             colpart, dbuf, rl);
  reduce_kernel<<<1, 256, 0, stream>>>(rl, out);
}

// Round 5
// 134.751 us; speedup vs baseline: 2.1137x; 2.1137x over previous
//
#include <hip/hip_runtime.h>
#include <hip/hip_bf16.h>
#include <math.h>

typedef __attribute__((ext_vector_type(8))) short short8;
typedef __attribute__((ext_vector_type(4))) float f32x4;

#define NB 8192
#define ND 256
#define NT 32             // 256-row tiles per side
#define TILE_USH 16384    // one 64-row K-major tile in ushorts
#define NBLK 528          // 32*33/2 triangle tiles
#define NSPLIT 8          // classsum row splits
#define LN2f 0.6931471805599453f

__device__ __forceinline__ float bf2f(ushort u) {
  unsigned int x = ((unsigned int)u) << 16;
  return __builtin_bit_cast(float, x);
}
__device__ __forceinline__ ushort f2bf(float x) {
  return __builtin_bit_cast(ushort, __float2bfloat16(x));
}

// ---- prep: normalize, fold 1/sqrt(T*ln2), quantize, exact ||q||^2;     ----
// ---- write row-major hs AND K-major tiles hsK[tile][u 0..31][r 0..63]  ----
__global__ void prep_kernel(const float* __restrict__ h, ushort* __restrict__ hs,
                            ushort* __restrict__ hsK, float* __restrict__ dbuf) {
  __shared__ ushort T[64 * 256];   // 32 KB, 16B-unit swizzled: slot = u ^ (r&31)
  const float SCALE = 1.0f / sqrtf(0.07f * 0.6931471805599453f);
  int tid = threadIdx.x, lane = tid & 63, wave = tid >> 6;
  int r0 = blockIdx.x * 64;

#pragma unroll 4
  for (int i = 0; i < 16; ++i) {
    int r = wave * 16 + i;
    const float4* rp = reinterpret_cast<const float4*>(h + (size_t)(r0 + r) * ND);
    float4 v = rp[lane];
    float ss = v.x * v.x + v.y * v.y + v.z * v.z + v.w * v.w;
#pragma unroll
    for (int d = 1; d <= 32; d <<= 1) ss += __shfl_xor(ss, d);
    float scale = SCALE / fmaxf(sqrtf(ss), 1e-12f);
    ushort4 o;
    o.x = f2bf(v.x * scale);
    o.y = f2bf(v.y * scale);
    o.z = f2bf(v.z * scale);
    o.w = f2bf(v.w * scale);
    reinterpret_cast<ushort4*>(hs + (size_t)(r0 + r) * ND)[lane] = o;
    int slot = (lane >> 1) ^ (r & 31);
    *reinterpret_cast<ushort4*>(
        reinterpret_cast<char*>(T) + r * 512 + slot * 16 + (lane & 1) * 8) = o;
    float qx = bf2f(o.x), qy = bf2f(o.y), qz = bf2f(o.z), qw = bf2f(o.w);
    float dd = qx * qx + qy * qy + qz * qz + qw * qw;
#pragma unroll
    for (int d = 1; d <= 32; d <<= 1) dd += __shfl_xor(dd, d);
    if (lane == 0) dbuf[r0 + r] = dd;
  }
  __syncthreads();
  ushort* dst = hsK + (size_t)blockIdx.x * TILE_USH;
#pragma unroll
  for (int k = 0; k < 8; ++k) {
    int S = k * 256 + tid;          // 16B chunk index: S = u*64 + r
    int r = S & 63, u = S >> 6;
    int slot = u ^ (r & 31);
    *reinterpret_cast<short8*>(dst + S * 8) = *reinterpret_cast<const short8*>(
        reinterpret_cast<const char*>(T) + r * 512 + slot * 16);
  }
}

// ---- per-class partial sums over a 1024-row slice (list-based, coalesced) --
__global__ void classsum_kernel(const ushort* __restrict__ hs,
                                const int* __restrict__ labels,
                                float* __restrict__ Csp, int* __restrict__ cntp) {
  __shared__ int list[1024];
  __shared__ int lcnt;
  int c = blockIdx.x, sp = blockIdx.y, t = threadIdx.x;
  if (t == 0) lcnt = 0;
  __syncthreads();
  int base = sp * (NB / NSPLIT);
#pragma unroll
  for (int i = t; i < NB / NSPLIT; i += 256)
    if (labels[base + i] == c) list[atomicAdd(&lcnt, 1)] = base + i;
  __syncthreads();
  int n = lcnt;
  float acc = 0.f;
  for (int k = 0; k < n; ++k)
    acc += bf2f(hs[(size_t)list[k] * ND + t]);
  Csp[((size_t)sp * 100 + c) * ND + t] = acc;
  if (t == 0) cntp[sp * 100 + c] = n;
}

// stage one 64-col K-major tile (32KB) into LDS: pure linear copy
__device__ __forceinline__ void stageB(ushort* lds, const ushort* gsrc,
                                       int wave, int lane) {
#pragma unroll
  for (int c = 0; c < 8; ++c) {
    int base = (wave * 8 + c) * 512;
    __builtin_amdgcn_global_load_lds(
        (const __attribute__((address_space(1))) unsigned int*)(gsrc + base + lane * 8),
        (__attribute__((address_space(3))) unsigned int*)(lds + base),
        16, 0, 0);
  }
}

// ---- main: triangle tiles; exp2 sums into row- and col-accumulators -------
__global__ __launch_bounds__(256, 2)
void main_kernel(const ushort* __restrict__ hsK,
                 float* __restrict__ rowpart, float* __restrict__ colpart) {
  __shared__ ushort Blds[2][64 * 256];   // 64 KB
  int tid = threadIdx.x, lane = tid & 63, wave = tid >> 6;
  int g = lane >> 4, cl = lane & 15;

  int nid = (blockIdx.x & 7) * 66 + (blockIdx.x >> 3);   // 528 = 8*66, bijective
  int rb = 0, t2 = nid;
  while (t2 >= NT - rb) { t2 -= NT - rb; ++rb; }
  int cb = rb + t2;
  bool diag = (rb == cb);

  const ushort* At = hsK + (size_t)(rb * 4 + wave) * TILE_USH;
  short8 af[4][8];
#pragma unroll
  for (int rf = 0; rf < 4; ++rf)
#pragma unroll
    for (int kk = 0; kk < 8; ++kk)
      af[rf][kk] = *reinterpret_cast<const short8*>(
          At + ((kk * 4 + g) * 64 + rf * 16 + cl) * 8);

  float s[16], ccum[16];
#pragma unroll
  for (int i = 0; i < 16; ++i) { s[i] = 0.f; ccum[i] = 0.f; }

  const ushort* Bbase = hsK + (size_t)(cb * 4) * TILE_USH;
  stageB(Blds[0], Bbase, wave, lane);
  __syncthreads();

  for (int it = 0; it < 4; ++it) {
    if (it + 1 < 4)
      stageB(Blds[(it + 1) & 1], Bbase + (size_t)(it + 1) * TILE_USH, wave, lane);
    const ushort* Bt = Blds[it & 1];

#pragma unroll
    for (int cf = 0; cf < 4; ++cf) {
      short8 bfr[8];
#pragma unroll
      for (int kk = 0; kk < 8; ++kk)
        bfr[kk] = *reinterpret_cast<const short8*>(
            Bt + ((kk * 4 + g) * 64 + cf * 16 + cl) * 8);
      f32x4 acc[4];
#pragma unroll
      for (int rf = 0; rf < 4; ++rf) acc[rf] = (f32x4){0.f, 0.f, 0.f, 0.f};
#pragma unroll
      for (int kk = 0; kk < 8; ++kk) {
#pragma unroll
        for (int rf = 0; rf < 4; ++rf)
          acc[rf] = __builtin_amdgcn_mfma_f32_16x16x32_bf16(af[rf][kk], bfr[kk],
                                                            acc[rf], 0, 0, 0);
      }
      float csum = 0.f;
#pragma unroll
      for (int rf = 0; rf < 4; ++rf)
#pragma unroll
        for (int q = 0; q < 4; ++q) {
          float e = __builtin_amdgcn_exp2f(acc[rf][q]);
          s[rf * 4 + q] += e;
          csum += e;
        }
      ccum[it * 4 + cf] = csum;
    }
    __syncthreads();   // drains prefetch vmcnt + protects Blds
  }

  // row partials: reduce over cl (this lane's 16-col subsets)
#pragma unroll
  for (int i = 0; i < 16; ++i) {
#pragma unroll
    for (int d = 1; d <= 8; d <<= 1) s[i] += __shfl_xor(s[i], d);
  }
  if (cl == 0) {
    int R0 = rb * 256 + wave * 64;
#pragma unroll
    for (int rf = 0; rf < 4; ++rf)
#pragma unroll
      for (int q = 0; q < 4; ++q)
        rowpart[(size_t)cb * NB + R0 + rf * 16 + g * 4 + q] = s[rf * 4 + q];
  }

  if (!diag) {
    // col partials: reduce over row-groups g (lane bits 4,5), then over waves
#pragma unroll
    for (int k = 0; k < 16; ++k) {
      ccum[k] += __shfl_xor(ccum[k], 16);
      ccum[k] += __shfl_xor(ccum[k], 32);
    }
    float* cr = reinterpret_cast<float*>(&Blds[0][0]);   // safe: Blds[0] dead
    if (g == 0) {
#pragma unroll
      for (int k = 0; k < 16; ++k) cr[(wave * 16 + k) * 16 + cl] = ccum[k];
    }
    __syncthreads();
    int k = tid >> 4, c2 = tid & 15;
    float v = cr[(0 * 16 + k) * 16 + c2] + cr[(1 * 16 + k) * 16 + c2] +
              cr[(2 * 16 + k) * 16 + c2] + cr[(3 * 16 + k) * 16 + c2];
    int col = cb * 256 + (k >> 2) * 64 + (k & 3) * 16 + c2;
    colpart[(size_t)rb * NB + col] = v;
  }
}

// ---- per-row loss ----------------------------------------------------------
__global__ void rowloss_kernel(const ushort* __restrict__ hs,
                               const int* __restrict__ labels,
                               const float* __restrict__ Csp,
                               const int* __restrict__ cntp,
                               const float* __restrict__ rowpart,
                               const float* __restrict__ colpart,
                               const float* __restrict__ dbuf,
                               float2* __restrict__ rl) {
  int lane = threadIdx.x & 63, wave = threadIdx.x >> 6;
  int row = blockIdx.x * 4 + wave;
  int lbl = labels[row];
  ushort4 qb = reinterpret_cast<const ushort4*>(hs + (size_t)row * ND)[lane];
  float4 cv = make_float4(0.f, 0.f, 0.f, 0.f);
  int ntot = 0;
#pragma unroll
  for (int sp = 0; sp < NSPLIT; ++sp) {
    float4 p = reinterpret_cast<const float4*>(
        Csp + ((size_t)sp * 100 + lbl) * ND)[lane];
    cv.x += p.x; cv.y += p.y; cv.z += p.z; cv.w += p.w;
    ntot += cntp[sp * 100 + lbl];
  }
  float dot = bf2f(qb.x) * cv.x + bf2f(qb.y) * cv.y +
              bf2f(qb.z) * cv.z + bf2f(qb.w) * cv.w;
#pragma unroll
  for (int d = 1; d <= 32; d <<= 1) dot += __shfl_xor(dot, d);

  int rb0 = row >> 8;
  float part = 0.f;
  if (lane < 32) {
    const float* base = (lane >= rb0) ? rowpart : colpart;
    part = base[(size_t)lane * NB + row];
  }
#pragma unroll
  for (int d = 1; d <= 16; d <<= 1) part += __shfl_xor(part, d);

  if (lane == 0) {
    float dself = dbuf[row];
    float s = part - (1.0f - 1e-8f) * __builtin_amdgcn_exp2f(dself);
    float denom2 = log2f(s);
    float Sp2 = dot - dself;
    float n = (float)ntot - 1.0f;
    float li = 0.f, val = 0.f;
    if (n > 0.5f) { li = -LN2f * (Sp2 - n * denom2) / n; val = 1.f; }
    rl[row] = make_float2(li, val);
  }
}

__global__ void reduce_kernel(const float2* __restrict__ rl, float* __restrict__ out) {
  int t = threadIdx.x;
  float L = 0.f, V = 0.f;
  for (int r = t; r < NB; r += 256) { float2 p = rl[r]; L += p.x; V += p.y; }
#pragma unroll
  for (int d = 1; d <= 32; d <<= 1) { L += __shfl_xor(L, d); V += __shfl_xor(V, d); }
  __shared__ float sL[4], sV[4];
  if ((t & 63) == 0) { sL[t >> 6] = L; sV[t >> 6] = V; }
  __syncthreads();
  if (t == 0)
    out[0] = (sL[0] + sL[1] + sL[2] + sL[3]) /
             fmaxf(sV[0] + sV[1] + sV[2] + sV[3], 1.f);
}

extern "C" void kernel_launch(void* const* d_in, const int* in_sizes, int n_in,
                              void* d_out, int out_size, void* d_ws, size_t ws_size,
                              hipStream_t stream) {
  const float* hidden = (const float*)d_in[0];
  const int* labels = (const int*)d_in[1];
  float* out = (float*)d_out;

  ushort* hsK     = (ushort*)d_ws;                         // 4 MB
  ushort* hs      = (ushort*)((char*)d_ws + 4194304);      // 4 MB
  float* dbuf     = (float*)((char*)d_ws + 8388608);       // 32 KB
  float* Csp      = (float*)((char*)d_ws + 8421376);       // 800 KB
  int* cntp       = (int*)((char*)d_ws + 9240576);         // 4 KB
  float* rowpart  = (float*)((char*)d_ws + 9244672);       // 1 MB
  float* colpart  = (float*)((char*)d_ws + 10293248);      // 1 MB
  float2* rl      = (float2*)((char*)d_ws + 11341824);     // 64 KB

  prep_kernel<<<NB / 64, 256, 0, stream>>>(hidden, hs, hsK, dbuf);
  classsum_kernel<<<dim3(100, NSPLIT), 256, 0, stream>>>(hs, labels, Csp, cntp);
  main_kernel<<<NBLK, 256, 0, stream>>>(hsK, rowpart, colpart);
  rowloss_kernel<<<NB / 4, 256, 0, stream>>>(hs, labels, Csp, cntp, rowpart,
                                             colpart, dbuf, rl);
  reduce_kernel<<<1, 256, 0, stream>>>(rl, out);
}

// Round 6
// 134.305 us; speedup vs baseline: 2.1207x; 1.0033x over previous
//
#include <hip/hip_runtime.h>
#include <hip/hip_bf16.h>
#include <math.h>

typedef __attribute__((ext_vector_type(8))) short short8;
typedef __attribute__((ext_vector_type(4))) float f32x4;

#define NB 8192
#define ND 256
#define NT 32             // 256-row tiles per side
#define TILE_USH 16384    // one 64-row K-major tile in ushorts
#define NBLK 528          // 32*33/2 triangle tiles
#define NSPLIT 8          // classsum row splits
#define LN2f 0.6931471805599453f

__device__ __forceinline__ float bf2f(ushort u) {
  unsigned int x = ((unsigned int)u) << 16;
  return __builtin_bit_cast(float, x);
}
__device__ __forceinline__ ushort f2bf(float x) {
  return __builtin_bit_cast(ushort, __float2bfloat16(x));
}

// ---- prep: normalize, fold 1/sqrt(T*ln2), quantize, exact ||q||^2;     ----
// ---- write row-major hs AND K-major tiles hsK[tile][u 0..31][r 0..63]  ----
__global__ void prep_kernel(const float* __restrict__ h, ushort* __restrict__ hs,
                            ushort* __restrict__ hsK, float* __restrict__ dbuf) {
  __shared__ ushort T[64 * 256];   // 32 KB, 16B-unit swizzled: slot = u ^ (r&31)
  const float SCALE = 1.0f / sqrtf(0.07f * 0.6931471805599453f);
  int tid = threadIdx.x, lane = tid & 63, wave = tid >> 6;
  int r0 = blockIdx.x * 64;

#pragma unroll 4
  for (int i = 0; i < 16; ++i) {
    int r = wave * 16 + i;
    const float4* rp = reinterpret_cast<const float4*>(h + (size_t)(r0 + r) * ND);
    float4 v = rp[lane];
    float ss = v.x * v.x + v.y * v.y + v.z * v.z + v.w * v.w;
#pragma unroll
    for (int d = 1; d <= 32; d <<= 1) ss += __shfl_xor(ss, d);
    float scale = SCALE / fmaxf(sqrtf(ss), 1e-12f);
    ushort4 o;
    o.x = f2bf(v.x * scale);
    o.y = f2bf(v.y * scale);
    o.z = f2bf(v.z * scale);
    o.w = f2bf(v.w * scale);
    reinterpret_cast<ushort4*>(hs + (size_t)(r0 + r) * ND)[lane] = o;
    int slot = (lane >> 1) ^ (r & 31);
    *reinterpret_cast<ushort4*>(
        reinterpret_cast<char*>(T) + r * 512 + slot * 16 + (lane & 1) * 8) = o;
    float qx = bf2f(o.x), qy = bf2f(o.y), qz = bf2f(o.z), qw = bf2f(o.w);
    float dd = qx * qx + qy * qy + qz * qz + qw * qw;
#pragma unroll
    for (int d = 1; d <= 32; d <<= 1) dd += __shfl_xor(dd, d);
    if (lane == 0) dbuf[r0 + r] = dd;
  }
  __syncthreads();
  ushort* dst = hsK + (size_t)blockIdx.x * TILE_USH;
#pragma unroll
  for (int k = 0; k < 8; ++k) {
    int S = k * 256 + tid;          // 16B chunk index: S = u*64 + r
    int r = S & 63, u = S >> 6;
    int slot = u ^ (r & 31);
    *reinterpret_cast<short8*>(dst + S * 8) = *reinterpret_cast<const short8*>(
        reinterpret_cast<const char*>(T) + r * 512 + slot * 16);
  }
}

// ---- per-class partial sums over a 1024-row slice (list-based, coalesced) --
__global__ void classsum_kernel(const ushort* __restrict__ hs,
                                const int* __restrict__ labels,
                                float* __restrict__ Csp, int* __restrict__ cntp) {
  __shared__ int list[1024];
  __shared__ int lcnt;
  int c = blockIdx.x, sp = blockIdx.y, t = threadIdx.x;
  if (t == 0) lcnt = 0;
  __syncthreads();
  int base = sp * (NB / NSPLIT);
#pragma unroll
  for (int i = t; i < NB / NSPLIT; i += 256)
    if (labels[base + i] == c) list[atomicAdd(&lcnt, 1)] = base + i;
  __syncthreads();
  int n = lcnt;
  float acc = 0.f;
  for (int k = 0; k < n; ++k)
    acc += bf2f(hs[(size_t)list[k] * ND + t]);
  Csp[((size_t)sp * 100 + c) * ND + t] = acc;
  if (t == 0) cntp[sp * 100 + c] = n;
}

// stage one 64-col K-major tile (32KB) into LDS: pure linear copy
__device__ __forceinline__ void stageB(ushort* lds, const ushort* gsrc,
                                       int wave, int lane) {
#pragma unroll
  for (int c = 0; c < 8; ++c) {
    int base = (wave * 8 + c) * 512;
    __builtin_amdgcn_global_load_lds(
        (const __attribute__((address_space(1))) unsigned int*)(gsrc + base + lane * 8),
        (__attribute__((address_space(3))) unsigned int*)(lds + base),
        16, 0, 0);
  }
}

// ---- main: triangle tiles; exp2 sums into row- and col-accumulators -------
__global__ __launch_bounds__(256, 2)
void main_kernel(const ushort* __restrict__ hsK,
                 float* __restrict__ rowpart, float* __restrict__ colpart) {
  __shared__ ushort Blds[2][64 * 256];   // 64 KB
  int tid = threadIdx.x, lane = tid & 63, wave = tid >> 6;
  int g = lane >> 4, cl = lane & 15;

  int nid = (blockIdx.x & 7) * 66 + (blockIdx.x >> 3);   // 528 = 8*66, bijective
  int rb = 0, t2 = nid;
  while (t2 >= NT - rb) { t2 -= NT - rb; ++rb; }
  int cb = rb + t2;
  bool diag = (rb == cb);

  const ushort* At = hsK + (size_t)(rb * 4 + wave) * TILE_USH;
  short8 af[4][8];
#pragma unroll
  for (int rf = 0; rf < 4; ++rf)
#pragma unroll
    for (int kk = 0; kk < 8; ++kk)
      af[rf][kk] = *reinterpret_cast<const short8*>(
          At + ((kk * 4 + g) * 64 + rf * 16 + cl) * 8);

  float s[16], ccum[16];
#pragma unroll
  for (int i = 0; i < 16; ++i) { s[i] = 0.f; ccum[i] = 0.f; }

  const ushort* Bbase = hsK + (size_t)(cb * 4) * TILE_USH;
  stageB(Blds[0], Bbase, wave, lane);
  __syncthreads();

#pragma unroll                        // CRITICAL: compile-time it -> ccum/s stay in VGPRs
  for (int it = 0; it < 4; ++it) {
    if (it + 1 < 4)
      stageB(Blds[(it + 1) & 1], Bbase + (size_t)(it + 1) * TILE_USH, wave, lane);
    const ushort* Bt = Blds[it & 1];

#pragma unroll
    for (int cf = 0; cf < 4; ++cf) {
      short8 bfr[8];
#pragma unroll
      for (int kk = 0; kk < 8; ++kk)
        bfr[kk] = *reinterpret_cast<const short8*>(
            Bt + ((kk * 4 + g) * 64 + cf * 16 + cl) * 8);
      f32x4 acc[4];
#pragma unroll
      for (int rf = 0; rf < 4; ++rf) acc[rf] = (f32x4){0.f, 0.f, 0.f, 0.f};
#pragma unroll
      for (int kk = 0; kk < 8; ++kk) {
#pragma unroll
        for (int rf = 0; rf < 4; ++rf)
          acc[rf] = __builtin_amdgcn_mfma_f32_16x16x32_bf16(af[rf][kk], bfr[kk],
                                                            acc[rf], 0, 0, 0);
      }
      float csum = 0.f;
#pragma unroll
      for (int rf = 0; rf < 4; ++rf)
#pragma unroll
        for (int q = 0; q < 4; ++q) {
          float e = __builtin_amdgcn_exp2f(acc[rf][q]);
          s[rf * 4 + q] += e;
          csum += e;
        }
      ccum[it * 4 + cf] += csum;
    }
    __syncthreads();   // drains prefetch vmcnt + protects Blds
  }

  // row partials: reduce over cl (this lane's 16-col subsets)
#pragma unroll
  for (int i = 0; i < 16; ++i) {
#pragma unroll
    for (int d = 1; d <= 8; d <<= 1) s[i] += __shfl_xor(s[i], d);
  }
  if (cl == 0) {
    int R0 = rb * 256 + wave * 64;
#pragma unroll
    for (int rf = 0; rf < 4; ++rf)
#pragma unroll
      for (int q = 0; q < 4; ++q)
        rowpart[(size_t)cb * NB + R0 + rf * 16 + g * 4 + q] = s[rf * 4 + q];
  }

  if (!diag) {
    // col partials: reduce over row-groups g (lane bits 4,5), then over waves
#pragma unroll
    for (int k = 0; k < 16; ++k) {
      ccum[k] += __shfl_xor(ccum[k], 16);
      ccum[k] += __shfl_xor(ccum[k], 32);
    }
    float* cr = reinterpret_cast<float*>(&Blds[0][0]);   // safe: Blds[0] dead
    if (g == 0) {
#pragma unroll
      for (int k = 0; k < 16; ++k) cr[(wave * 16 + k) * 16 + cl] = ccum[k];
    }
    __syncthreads();
    int k = tid >> 4, c2 = tid & 15;
    float v = cr[(0 * 16 + k) * 16 + c2] + cr[(1 * 16 + k) * 16 + c2] +
              cr[(2 * 16 + k) * 16 + c2] + cr[(3 * 16 + k) * 16 + c2];
    int col = cb * 256 + (k >> 2) * 64 + (k & 3) * 16 + c2;
    colpart[(size_t)rb * NB + col] = v;
  }
}

// ---- per-row loss ----------------------------------------------------------
__global__ void rowloss_kernel(const ushort* __restrict__ hs,
                               const int* __restrict__ labels,
                               const float* __restrict__ Csp,
                               const int* __restrict__ cntp,
                               const float* __restrict__ rowpart,
                               const float* __restrict__ colpart,
                               const float* __restrict__ dbuf,
                               float2* __restrict__ rl) {
  int lane = threadIdx.x & 63, wave = threadIdx.x >> 6;
  int row = blockIdx.x * 4 + wave;
  int lbl = labels[row];
  ushort4 qb = reinterpret_cast<const ushort4*>(hs + (size_t)row * ND)[lane];
  float4 cv = make_float4(0.f, 0.f, 0.f, 0.f);
  int ntot = 0;
#pragma unroll
  for (int sp = 0; sp < NSPLIT; ++sp) {
    float4 p = reinterpret_cast<const float4*>(
        Csp + ((size_t)sp * 100 + lbl) * ND)[lane];
    cv.x += p.x; cv.y += p.y; cv.z += p.z; cv.w += p.w;
    ntot += cntp[sp * 100 + lbl];
  }
  float dot = bf2f(qb.x) * cv.x + bf2f(qb.y) * cv.y +
              bf2f(qb.z) * cv.z + bf2f(qb.w) * cv.w;
#pragma unroll
  for (int d = 1; d <= 32; d <<= 1) dot += __shfl_xor(dot, d);

  int rb0 = row >> 8;
  float part = 0.f;
  if (lane < 32) {
    const float* base = (lane >= rb0) ? rowpart : colpart;
    part = base[(size_t)lane * NB + row];
  }
#pragma unroll
  for (int d = 1; d <= 16; d <<= 1) part += __shfl_xor(part, d);

  if (lane == 0) {
    float dself = dbuf[row];
    float s = part - (1.0f - 1e-8f) * __builtin_amdgcn_exp2f(dself);
    float denom2 = log2f(s);
    float Sp2 = dot - dself;
    float n = (float)ntot - 1.0f;
    float li = 0.f, val = 0.f;
    if (n > 0.5f) { li = -LN2f * (Sp2 - n * denom2) / n; val = 1.f; }
    rl[row] = make_float2(li, val);
  }
}

__global__ void reduce_kernel(const float2* __restrict__ rl, float* __restrict__ out) {
  int t = threadIdx.x;
  float L = 0.f, V = 0.f;
  for (int r = t; r < NB; r += 256) { float2 p = rl[r]; L += p.x; V += p.y; }
#pragma unroll
  for (int d = 1; d <= 32; d <<= 1) { L += __shfl_xor(L, d); V += __shfl_xor(V, d); }
  __shared__ float sL[4], sV[4];
  if ((t & 63) == 0) { sL[t >> 6] = L; sV[t >> 6] = V; }
  __syncthreads();
  if (t == 0)
    out[0] = (sL[0] + sL[1] + sL[2] + sL[3]) /
             fmaxf(sV[0] + sV[1] + sV[2] + sV[3], 1.f);
}

extern "C" void kernel_launch(void* const* d_in, const int* in_sizes, int n_in,
                              void* d_out, int out_size, void* d_ws, size_t ws_size,
                              hipStream_t stream) {
  const float* hidden = (const float*)d_in[0];
  const int* labels = (const int*)d_in[1];
  float* out = (float*)d_out;

  ushort* hsK     = (ushort*)d_ws;                         // 4 MB
  ushort* hs      = (ushort*)((char*)d_ws + 4194304);      // 4 MB
  float* dbuf     = (float*)((char*)d_ws + 8388608);       // 32 KB
  float* Csp      = (float*)((char*)d_ws + 8421376);       // 800 KB
  int* cntp       = (int*)((char*)d_ws + 9240576);         // 4 KB
  float* rowpart  = (float*)((char*)d_ws + 9244672);       // 1 MB
  float* colpart  = (float*)((char*)d_ws + 10293248);      // 1 MB
  float2* rl      = (float2*)((char*)d_ws + 11341824);     // 64 KB

  prep_kernel<<<NB / 64, 256, 0, stream>>>(hidden, hs, hsK, dbuf);
  classsum_kernel<<<dim3(100, NSPLIT), 256, 0, stream>>>(hs, labels, Csp, cntp);
  main_kernel<<<NBLK, 256, 0, stream>>>(hsK, rowpart, colpart);
  rowloss_kernel<<<NB / 4, 256, 0, stream>>>(hs, labels, Csp, cntp, rowpart,
                                             colpart, dbuf, rl);
  reduce_kernel<<<1, 256, 0, stream>>>(rl, out);
}

// Round 7
// 83.886 us; speedup vs baseline: 3.3953x; 1.6010x over previous
//
#include <hip/hip_runtime.h>
#include <hip/hip_bf16.h>
#include <math.h>

typedef __attribute__((ext_vector_type(8))) short short8;
typedef __attribute__((ext_vector_type(4))) float f32x4;

#define NB 8192
#define ND 256
#define NT2 64            // 128-row tiles per side
#define NBLK2 2080        // 64*65/2 triangle tiles
#define CHUNK_USH 8192    // one (tile,chunk) = 8 units x 128 rows x 8 ushorts = 16KB
#define TILE2_USH 32768   // 4 chunks
#define NSPLIT 8          // classsum row splits
#define LN2f 0.6931471805599453f

__device__ __forceinline__ float bf2f(ushort u) {
  unsigned int x = ((unsigned int)u) << 16;
  return __builtin_bit_cast(float, x);
}
__device__ __forceinline__ ushort f2bf(float x) {
  return __builtin_bit_cast(ushort, __float2bfloat16(x));
}

// ---- prep: normalize, fold 1/sqrt(T*ln2), quantize, exact ||q||^2;      ----
// ---- write row-major hs AND chunked K-major hsK[tile128][chunk][u][row] ----
__global__ void prep_kernel(const float* __restrict__ h, ushort* __restrict__ hs,
                            ushort* __restrict__ hsK, float* __restrict__ dbuf) {
  __shared__ ushort T[128 * 256];  // 64 KB, swizzled 16B units: slot = ku ^ (r&31)
  const float SCALE = 1.0f / sqrtf(0.07f * 0.6931471805599453f);
  int tid = threadIdx.x, lane = tid & 63, wave = tid >> 6;
  int r0 = blockIdx.x * 128;

#pragma unroll 4
  for (int i = 0; i < 32; ++i) {
    int r = wave * 32 + i;
    const float4* rp = reinterpret_cast<const float4*>(h + (size_t)(r0 + r) * ND);
    float4 v = rp[lane];
    float ss = v.x * v.x + v.y * v.y + v.z * v.z + v.w * v.w;
#pragma unroll
    for (int d = 1; d <= 32; d <<= 1) ss += __shfl_xor(ss, d);
    float scale = SCALE / fmaxf(sqrtf(ss), 1e-12f);
    ushort4 o;
    o.x = f2bf(v.x * scale);
    o.y = f2bf(v.y * scale);
    o.z = f2bf(v.z * scale);
    o.w = f2bf(v.w * scale);
    reinterpret_cast<ushort4*>(hs + (size_t)(r0 + r) * ND)[lane] = o;
    int slot = (lane >> 1) ^ (r & 31);
    *reinterpret_cast<ushort4*>(
        reinterpret_cast<char*>(T) + r * 512 + slot * 16 + (lane & 1) * 8) = o;
    float qx = bf2f(o.x), qy = bf2f(o.y), qz = bf2f(o.z), qw = bf2f(o.w);
    float dd = qx * qx + qy * qy + qz * qz + qw * qw;
#pragma unroll
    for (int d = 1; d <= 32; d <<= 1) dd += __shfl_xor(dd, d);
    if (lane == 0) dbuf[r0 + r] = dd;
  }
  __syncthreads();
  ushort* dst = hsK + (size_t)blockIdx.x * TILE2_USH;
#pragma unroll
  for (int s2 = 0; s2 < 16; ++s2) {
    int U = s2 * 256 + tid;          // linear (chunk,u,row) 16B-unit index
    int row = U & 127, u = (U >> 7) & 7, chunk = U >> 10;
    int ku = chunk * 8 + u;          // 16B unit within original row (0..31)
    int slot = ku ^ (row & 31);
    *reinterpret_cast<short8*>(dst + (size_t)U * 8) =
        *reinterpret_cast<const short8*>(
            reinterpret_cast<const char*>(T) + row * 512 + slot * 16);
  }
}

// ---- per-class partial sums over a 1024-row slice (list-based, coalesced) --
__global__ void classsum_kernel(const ushort* __restrict__ hs,
                                const int* __restrict__ labels,
                                float* __restrict__ Csp, int* __restrict__ cntp) {
  __shared__ int list[1024];
  __shared__ int lcnt;
  int c = blockIdx.x, sp = blockIdx.y, t = threadIdx.x;
  if (t == 0) lcnt = 0;
  __syncthreads();
  int base = sp * (NB / NSPLIT);
#pragma unroll
  for (int i = t; i < NB / NSPLIT; i += 256)
    if (labels[base + i] == c) list[atomicAdd(&lcnt, 1)] = base + i;
  __syncthreads();
  int n = lcnt;
  float acc = 0.f;
  for (int k = 0; k < n; ++k)
    acc += bf2f(hs[(size_t)list[k] * ND + t]);
  Csp[((size_t)sp * 100 + c) * ND + t] = acc;
  if (t == 0) cntp[sp * 100 + c] = n;
}

// stage one 16KB chunk into LDS: pure linear copy (1024 16B units)
__device__ __forceinline__ void stageC(ushort* lds, const ushort* gsrc, int tid) {
#pragma unroll
  for (int i = 0; i < 4; ++i) {
    int u = i * 256 + tid;
    __builtin_amdgcn_global_load_lds(
        (const __attribute__((address_space(1))) unsigned int*)(gsrc + (size_t)u * 8),
        (__attribute__((address_space(3))) unsigned int*)(lds + (size_t)u * 8),
        16, 0, 0);
  }
}

// ---- main: 128x128 triangle tiles, K-streamed, exp2 in epilogue -----------
__global__ __launch_bounds__(256, 2)
void main_kernel(const ushort* __restrict__ hsK,
                 float* __restrict__ rowpart, float* __restrict__ colpart) {
  __shared__ ushort Ach[2][CHUNK_USH];   // 32 KB
  __shared__ ushort Bch[2][CHUNK_USH];   // 32 KB
  int tid = threadIdx.x, lane = tid & 63, wave = tid >> 6;
  int g = lane >> 4, cl = lane & 15;

  int nid = (blockIdx.x & 7) * 260 + (blockIdx.x >> 3);  // 2080 = 8*260, bijective
  int rb = 0, t2 = nid;
  while (t2 >= NT2 - rb) { t2 -= NT2 - rb; ++rb; }
  int cb = rb + t2;
  bool diag = (rb == cb);
  int rhalf = wave >> 1, chalf = wave & 1;
  int wr = rhalf * 64, wc = chalf * 64;

  const ushort* Ag = hsK + (size_t)rb * TILE2_USH;
  const ushort* Bg = hsK + (size_t)cb * TILE2_USH;

  stageC(Ach[0], Ag, tid);
  if (!diag) stageC(Bch[0], Bg, tid);
  __syncthreads();

  f32x4 acc[4][4];
#pragma unroll
  for (int rf = 0; rf < 4; ++rf)
#pragma unroll
    for (int cf = 0; cf < 4; ++cf) acc[rf][cf] = (f32x4){0.f, 0.f, 0.f, 0.f};

#pragma unroll
  for (int ch = 0; ch < 4; ++ch) {
    if (ch < 3) {
      stageC(Ach[(ch + 1) & 1], Ag + (size_t)(ch + 1) * CHUNK_USH, tid);
      if (!diag) stageC(Bch[(ch + 1) & 1], Bg + (size_t)(ch + 1) * CHUNK_USH, tid);
    }
    const ushort* At = Ach[ch & 1];
    const ushort* Bt = diag ? Ach[ch & 1] : Bch[ch & 1];
#pragma unroll
    for (int ks = 0; ks < 2; ++ks) {
      short8 af[4], bf[4];
#pragma unroll
      for (int rf = 0; rf < 4; ++rf)
        af[rf] = *reinterpret_cast<const short8*>(
            At + ((ks * 4 + g) * 128 + wr + rf * 16 + cl) * 8);
#pragma unroll
      for (int cf = 0; cf < 4; ++cf)
        bf[cf] = *reinterpret_cast<const short8*>(
            Bt + ((ks * 4 + g) * 128 + wc + cf * 16 + cl) * 8);
#pragma unroll
      for (int rf = 0; rf < 4; ++rf)
#pragma unroll
        for (int cf = 0; cf < 4; ++cf)
          acc[rf][cf] = __builtin_amdgcn_mfma_f32_16x16x32_bf16(af[rf], bf[cf],
                                                                acc[rf][cf], 0, 0, 0);
    }
    __syncthreads();   // drains prefetch vmcnt + protects buffers
  }

  // epilogue: e = exp2(acc); row sums (over cf,cl) and col sums (over rf,q,g)
  float sr[16], cc[4];
#pragma unroll
  for (int i = 0; i < 16; ++i) sr[i] = 0.f;
#pragma unroll
  for (int i = 0; i < 4; ++i) cc[i] = 0.f;
#pragma unroll
  for (int rf = 0; rf < 4; ++rf)
#pragma unroll
    for (int cf = 0; cf < 4; ++cf)
#pragma unroll
      for (int q = 0; q < 4; ++q) {
        float e = __builtin_amdgcn_exp2f(acc[rf][cf][q]);
        sr[rf * 4 + q] += e;
        cc[cf] += e;
      }
#pragma unroll
  for (int i = 0; i < 16; ++i) {
#pragma unroll
    for (int d = 1; d <= 8; d <<= 1) sr[i] += __shfl_xor(sr[i], d);
  }
#pragma unroll
  for (int i = 0; i < 4; ++i) {
    cc[i] += __shfl_xor(cc[i], 16);
    cc[i] += __shfl_xor(cc[i], 32);
  }

  float* red = reinterpret_cast<float*>(&Ach[0][0]);  // dead after K-loop barrier
  float* srow = red;        // [4 waves][64 rows]
  float* scol = red + 256;  // [4 waves][64 cols]
  if (cl == 0) {
#pragma unroll
    for (int rf = 0; rf < 4; ++rf)
#pragma unroll
      for (int q = 0; q < 4; ++q)
        srow[wave * 64 + rf * 16 + g * 4 + q] = sr[rf * 4 + q];
  }
  if (g == 0) {
#pragma unroll
    for (int cf = 0; cf < 4; ++cf) scol[wave * 64 + cf * 16 + cl] = cc[cf];
  }
  __syncthreads();
  if (tid < 128) {
    int half = tid >> 6, idx = tid & 63;
    float rv = srow[(half * 2 + 0) * 64 + idx] + srow[(half * 2 + 1) * 64 + idx];
    rowpart[(size_t)cb * NB + rb * 128 + half * 64 + idx] = rv;
    if (!diag) {
      float cv2 = scol[(half)*64 + idx] + scol[(half + 2) * 64 + idx];
      colpart[(size_t)rb * NB + cb * 128 + half * 64 + idx] = cv2;
    }
  }
}

// ---- per-row loss ----------------------------------------------------------
__global__ void rowloss_kernel(const ushort* __restrict__ hs,
                               const int* __restrict__ labels,
                               const float* __restrict__ Csp,
                               const int* __restrict__ cntp,
                               const float* __restrict__ rowpart,
                               const float* __restrict__ colpart,
                               const float* __restrict__ dbuf,
                               float2* __restrict__ rl) {
  int lane = threadIdx.x & 63, wave = threadIdx.x >> 6;
  int row = blockIdx.x * 4 + wave;
  int lbl = labels[row];
  ushort4 qb = reinterpret_cast<const ushort4*>(hs + (size_t)row * ND)[lane];
  float4 cv = make_float4(0.f, 0.f, 0.f, 0.f);
  int ntot = 0;
#pragma unroll
  for (int sp = 0; sp < NSPLIT; ++sp) {
    float4 p = reinterpret_cast<const float4*>(
        Csp + ((size_t)sp * 100 + lbl) * ND)[lane];
    cv.x += p.x; cv.y += p.y; cv.z += p.z; cv.w += p.w;
    ntot += cntp[sp * 100 + lbl];
  }
  float dot = bf2f(qb.x) * cv.x + bf2f(qb.y) * cv.y +
              bf2f(qb.z) * cv.z + bf2f(qb.w) * cv.w;
#pragma unroll
  for (int d = 1; d <= 32; d <<= 1) dot += __shfl_xor(dot, d);

  int rb0 = row >> 7;   // this row's 128-tile index
  const float* basep = (lane >= rb0) ? rowpart : colpart;
  float part = basep[(size_t)lane * NB + row];
#pragma unroll
  for (int d = 1; d <= 32; d <<= 1) part += __shfl_xor(part, d);

  if (lane == 0) {
    float dself = dbuf[row];
    float s = part - (1.0f - 1e-8f) * __builtin_amdgcn_exp2f(dself);
    float denom2 = log2f(s);
    float Sp2 = dot - dself;
    float n = (float)ntot - 1.0f;
    float li = 0.f, val = 0.f;
    if (n > 0.5f) { li = -LN2f * (Sp2 - n * denom2) / n; val = 1.f; }
    rl[row] = make_float2(li, val);
  }
}

__global__ __launch_bounds__(1024)
void reduce_kernel(const float2* __restrict__ rl, float* __restrict__ out) {
  int t = threadIdx.x;
  float L = 0.f, V = 0.f;
  for (int r = t; r < NB; r += 1024) { float2 p = rl[r]; L += p.x; V += p.y; }
#pragma unroll
  for (int d = 1; d <= 32; d <<= 1) { L += __shfl_xor(L, d); V += __shfl_xor(V, d); }
  __shared__ float sL[16], sV[16];
  if ((t & 63) == 0) { sL[t >> 6] = L; sV[t >> 6] = V; }
  __syncthreads();
  if (t == 0) {
    float Ls = 0.f, Vs = 0.f;
#pragma unroll
    for (int i = 0; i < 16; ++i) { Ls += sL[i]; Vs += sV[i]; }
    out[0] = Ls / fmaxf(Vs, 1.f);
  }
}

extern "C" void kernel_launch(void* const* d_in, const int* in_sizes, int n_in,
                              void* d_out, int out_size, void* d_ws, size_t ws_size,
                              hipStream_t stream) {
  const float* hidden = (const float*)d_in[0];
  const int* labels = (const int*)d_in[1];
  float* out = (float*)d_out;

  ushort* hsK     = (ushort*)d_ws;                         // 4 MB
  ushort* hs      = (ushort*)((char*)d_ws + 4194304);      // 4 MB
  float* dbuf     = (float*)((char*)d_ws + 8388608);       // 32 KB
  float* Csp      = (float*)((char*)d_ws + 8421376);       // 800 KB
  int* cntp       = (int*)((char*)d_ws + 9240576);         // 4 KB
  float* rowpart  = (float*)((char*)d_ws + 9244672);       // 2 MB
  float* colpart  = (float*)((char*)d_ws + 11341824);      // 2 MB
  float2* rl      = (float2*)((char*)d_ws + 13438976);     // 64 KB

  prep_kernel<<<NB / 128, 256, 0, stream>>>(hidden, hs, hsK, dbuf);
  classsum_kernel<<<dim3(100, NSPLIT), 256, 0, stream>>>(hs, labels, Csp, cntp);
  main_kernel<<<NBLK2, 256, 0, stream>>>(hsK, rowpart, colpart);
  rowloss_kernel<<<NB / 4, 256, 0, stream>>>(hs, labels, Csp, cntp, rowpart,
                                             colpart, dbuf, rl);
  reduce_kernel<<<1, 1024, 0, stream>>>(rl, out);
}

// Round 8
// 66.382 us; speedup vs baseline: 4.2905x; 1.2637x over previous
//
#include <hip/hip_runtime.h>
#include <hip/hip_bf16.h>
#include <math.h>

typedef __attribute__((ext_vector_type(8))) short short8;
typedef __attribute__((ext_vector_type(4))) float f32x4;

#define NB 8192
#define ND 256
#define NT2 64            // 128-row tiles per side
#define NBLK2 2080        // 64*65/2 triangle tiles
#define CHUNK_USH 8192    // one (tile,chunk) = 8 units x 128 rows x 8 ushorts = 16KB
#define TILE2_USH 32768   // 4 chunks
#define NSPLIT 8          // classsum row splits
#define LN2f 0.6931471805599453f

__device__ __forceinline__ float bf2f(ushort u) {
  unsigned int x = ((unsigned int)u) << 16;
  return __builtin_bit_cast(float, x);
}
__device__ __forceinline__ ushort f2bf(float x) {
  return __builtin_bit_cast(ushort, __float2bfloat16(x));
}

// ---- norm: normalize rows, fold 1/sqrt(T*ln2), quantize bf16, exact ||q||^2 ----
__global__ void norm_kernel(const float* __restrict__ h, ushort* __restrict__ hs,
                            float* __restrict__ dbuf) {
  const float SCALE = 1.0f / sqrtf(0.07f * 0.6931471805599453f);
  int lane = threadIdx.x & 63;
  int wave = threadIdx.x >> 6;
  int row = blockIdx.x * 4 + wave;
  const float4* rp = reinterpret_cast<const float4*>(h + (size_t)row * ND);
  float4 v = rp[lane];
  float ss = v.x * v.x + v.y * v.y + v.z * v.z + v.w * v.w;
#pragma unroll
  for (int d = 1; d <= 32; d <<= 1) ss += __shfl_xor(ss, d);
  float scale = SCALE / fmaxf(sqrtf(ss), 1e-12f);
  ushort4 o;
  o.x = f2bf(v.x * scale);
  o.y = f2bf(v.y * scale);
  o.z = f2bf(v.z * scale);
  o.w = f2bf(v.w * scale);
  reinterpret_cast<ushort4*>(hs + (size_t)row * ND)[lane] = o;
  float qx = bf2f(o.x), qy = bf2f(o.y), qz = bf2f(o.z), qw = bf2f(o.w);
  float dd = qx * qx + qy * qy + qz * qz + qw * qw;   // exact ||q||^2 (log2 units)
#pragma unroll
  for (int d = 1; d <= 32; d <<= 1) dd += __shfl_xor(dd, d);
  if (lane == 0) dbuf[row] = dd;
}

// ---- transpose: global->global 16B-unit permutation into chunked K-major ----
// hsK unit index within tile: U = ku*128 + row  (ku = chunk*8 + u, 0..31)
__global__ void transpose_kernel(const ushort* __restrict__ hs,
                                 ushort* __restrict__ hsK) {
  int gidx = blockIdx.x * 256 + threadIdx.x;     // 262144 units total
  int tile = gidx >> 12;                         // 4096 units per 128-row tile
  int U = gidx & 4095;
  int row = U & 127;
  int ku = U >> 7;                               // 0..31
  // dst is linear in gidx (coalesced); src is 512B-stride gather (L2-resident)
  *reinterpret_cast<short8*>(hsK + (size_t)gidx * 8) =
      *reinterpret_cast<const short8*>(
          hs + ((size_t)(tile * 128 + row) * ND) + ku * 8);
}

// ---- per-class partial sums over a 1024-row slice (list-based, coalesced) --
__global__ void classsum_kernel(const ushort* __restrict__ hs,
                                const int* __restrict__ labels,
                                float* __restrict__ Csp, int* __restrict__ cntp) {
  __shared__ int list[1024];
  __shared__ int lcnt;
  int c = blockIdx.x, sp = blockIdx.y, t = threadIdx.x;
  if (t == 0) lcnt = 0;
  __syncthreads();
  int base = sp * (NB / NSPLIT);
#pragma unroll
  for (int i = t; i < NB / NSPLIT; i += 256)
    if (labels[base + i] == c) list[atomicAdd(&lcnt, 1)] = base + i;
  __syncthreads();
  int n = lcnt;
  float acc = 0.f;
  for (int k = 0; k < n; ++k)
    acc += bf2f(hs[(size_t)list[k] * ND + t]);
  Csp[((size_t)sp * 100 + c) * ND + t] = acc;
  if (t == 0) cntp[sp * 100 + c] = n;
}

// stage one 16KB chunk into LDS: pure linear copy (1024 16B units)
__device__ __forceinline__ void stageC(ushort* lds, const ushort* gsrc, int tid) {
#pragma unroll
  for (int i = 0; i < 4; ++i) {
    int u = i * 256 + tid;
    __builtin_amdgcn_global_load_lds(
        (const __attribute__((address_space(1))) unsigned int*)(gsrc + (size_t)u * 8),
        (__attribute__((address_space(3))) unsigned int*)(lds + (size_t)u * 8),
        16, 0, 0);
  }
}

// ---- main: 128x128 triangle tiles, K-streamed, exp2 in epilogue -----------
__global__ __launch_bounds__(256, 2)
void main_kernel(const ushort* __restrict__ hsK,
                 float* __restrict__ rowpart, float* __restrict__ colpart) {
  __shared__ ushort Ach[2][CHUNK_USH];   // 32 KB
  __shared__ ushort Bch[2][CHUNK_USH];   // 32 KB
  int tid = threadIdx.x, lane = tid & 63, wave = tid >> 6;
  int g = lane >> 4, cl = lane & 15;

  int nid = (blockIdx.x & 7) * 260 + (blockIdx.x >> 3);  // 2080 = 8*260, bijective
  int rb = 0, t2 = nid;
  while (t2 >= NT2 - rb) { t2 -= NT2 - rb; ++rb; }
  int cb = rb + t2;
  bool diag = (rb == cb);
  int rhalf = wave >> 1, chalf = wave & 1;
  int wr = rhalf * 64, wc = chalf * 64;

  const ushort* Ag = hsK + (size_t)rb * TILE2_USH;
  const ushort* Bg = hsK + (size_t)cb * TILE2_USH;

  stageC(Ach[0], Ag, tid);
  if (!diag) stageC(Bch[0], Bg, tid);
  __syncthreads();

  f32x4 acc[4][4];
#pragma unroll
  for (int rf = 0; rf < 4; ++rf)
#pragma unroll
    for (int cf = 0; cf < 4; ++cf) acc[rf][cf] = (f32x4){0.f, 0.f, 0.f, 0.f};

#pragma unroll
  for (int ch = 0; ch < 4; ++ch) {
    if (ch < 3) {
      stageC(Ach[(ch + 1) & 1], Ag + (size_t)(ch + 1) * CHUNK_USH, tid);
      if (!diag) stageC(Bch[(ch + 1) & 1], Bg + (size_t)(ch + 1) * CHUNK_USH, tid);
    }
    const ushort* At = Ach[ch & 1];
    const ushort* Bt = diag ? Ach[ch & 1] : Bch[ch & 1];
#pragma unroll
    for (int ks = 0; ks < 2; ++ks) {
      short8 af[4], bf[4];
#pragma unroll
      for (int rf = 0; rf < 4; ++rf)
        af[rf] = *reinterpret_cast<const short8*>(
            At + ((ks * 4 + g) * 128 + wr + rf * 16 + cl) * 8);
#pragma unroll
      for (int cf = 0; cf < 4; ++cf)
        bf[cf] = *reinterpret_cast<const short8*>(
            Bt + ((ks * 4 + g) * 128 + wc + cf * 16 + cl) * 8);
#pragma unroll
      for (int rf = 0; rf < 4; ++rf)
#pragma unroll
        for (int cf = 0; cf < 4; ++cf)
          acc[rf][cf] = __builtin_amdgcn_mfma_f32_16x16x32_bf16(af[rf], bf[cf],
                                                                acc[rf][cf], 0, 0, 0);
    }
    __syncthreads();   // drains prefetch vmcnt + protects buffers
  }

  // epilogue: e = exp2(acc); row sums (over cf,cl) and col sums (over rf,q,g)
  float sr[16], cc[4];
#pragma unroll
  for (int i = 0; i < 16; ++i) sr[i] = 0.f;
#pragma unroll
  for (int i = 0; i < 4; ++i) cc[i] = 0.f;
#pragma unroll
  for (int rf = 0; rf < 4; ++rf)
#pragma unroll
    for (int cf = 0; cf < 4; ++cf)
#pragma unroll
      for (int q = 0; q < 4; ++q) {
        float e = __builtin_amdgcn_exp2f(acc[rf][cf][q]);
        sr[rf * 4 + q] += e;
        cc[cf] += e;
      }
#pragma unroll
  for (int i = 0; i < 16; ++i) {
#pragma unroll
    for (int d = 1; d <= 8; d <<= 1) sr[i] += __shfl_xor(sr[i], d);
  }
#pragma unroll
  for (int i = 0; i < 4; ++i) {
    cc[i] += __shfl_xor(cc[i], 16);
    cc[i] += __shfl_xor(cc[i], 32);
  }

  float* red = reinterpret_cast<float*>(&Ach[0][0]);  // dead after K-loop barrier
  float* srow = red;        // [4 waves][64 rows]
  float* scol = red + 256;  // [4 waves][64 cols]
  if (cl == 0) {
#pragma unroll
    for (int rf = 0; rf < 4; ++rf)
#pragma unroll
      for (int q = 0; q < 4; ++q)
        srow[wave * 64 + rf * 16 + g * 4 + q] = sr[rf * 4 + q];
  }
  if (g == 0) {
#pragma unroll
    for (int cf = 0; cf < 4; ++cf) scol[wave * 64 + cf * 16 + cl] = cc[cf];
  }
  __syncthreads();
  if (tid < 128) {
    int half = tid >> 6, idx = tid & 63;
    float rv = srow[(half * 2 + 0) * 64 + idx] + srow[(half * 2 + 1) * 64 + idx];
    rowpart[(size_t)cb * NB + rb * 128 + half * 64 + idx] = rv;
    if (!diag) {
      float cv2 = scol[(half)*64 + idx] + scol[(half + 2) * 64 + idx];
      colpart[(size_t)rb * NB + cb * 128 + half * 64 + idx] = cv2;
    }
  }
}

// ---- per-row loss ----------------------------------------------------------
__global__ void rowloss_kernel(const ushort* __restrict__ hs,
                               const int* __restrict__ labels,
                               const float* __restrict__ Csp,
                               const int* __restrict__ cntp,
                               const float* __restrict__ rowpart,
                               const float* __restrict__ colpart,
                               const float* __restrict__ dbuf,
                               float2* __restrict__ rl) {
  int lane = threadIdx.x & 63, wave = threadIdx.x >> 6;
  int row = blockIdx.x * 4 + wave;
  int lbl = labels[row];
  ushort4 qb = reinterpret_cast<const ushort4*>(hs + (size_t)row * ND)[lane];
  float4 cv = make_float4(0.f, 0.f, 0.f, 0.f);
  int ntot = 0;
#pragma unroll
  for (int sp = 0; sp < NSPLIT; ++sp) {
    float4 p = reinterpret_cast<const float4*>(
        Csp + ((size_t)sp * 100 + lbl) * ND)[lane];
    cv.x += p.x; cv.y += p.y; cv.z += p.z; cv.w += p.w;
    ntot += cntp[sp * 100 + lbl];
  }
  float dot = bf2f(qb.x) * cv.x + bf2f(qb.y) * cv.y +
              bf2f(qb.z) * cv.z + bf2f(qb.w) * cv.w;
#pragma unroll
  for (int d = 1; d <= 32; d <<= 1) dot += __shfl_xor(dot, d);

  int rb0 = row >> 7;   // this row's 128-tile index
  const float* basep = (lane >= rb0) ? rowpart : colpart;
  float part = basep[(size_t)lane * NB + row];
#pragma unroll
  for (int d = 1; d <= 32; d <<= 1) part += __shfl_xor(part, d);

  if (lane == 0) {
    float dself = dbuf[row];
    float s = part - (1.0f - 1e-8f) * __builtin_amdgcn_exp2f(dself);
    float denom2 = log2f(s);
    float Sp2 = dot - dself;
    float n = (float)ntot - 1.0f;
    float li = 0.f, val = 0.f;
    if (n > 0.5f) { li = -LN2f * (Sp2 - n * denom2) / n; val = 1.f; }
    rl[row] = make_float2(li, val);
  }
}

__global__ __launch_bounds__(1024)
void reduce_kernel(const float2* __restrict__ rl, float* __restrict__ out) {
  int t = threadIdx.x;
  float L = 0.f, V = 0.f;
  for (int r = t; r < NB; r += 1024) { float2 p = rl[r]; L += p.x; V += p.y; }
#pragma unroll
  for (int d = 1; d <= 32; d <<= 1) { L += __shfl_xor(L, d); V += __shfl_xor(V, d); }
  __shared__ float sL[16], sV[16];
  if ((t & 63) == 0) { sL[t >> 6] = L; sV[t >> 6] = V; }
  __syncthreads();
  if (t == 0) {
    float Ls = 0.f, Vs = 0.f;
#pragma unroll
    for (int i = 0; i < 16; ++i) { Ls += sL[i]; Vs += sV[i]; }
    out[0] = Ls / fmaxf(Vs, 1.f);
  }
}

extern "C" void kernel_launch(void* const* d_in, const int* in_sizes, int n_in,
                              void* d_out, int out_size, void* d_ws, size_t ws_size,
                              hipStream_t stream) {
  const float* hidden = (const float*)d_in[0];
  const int* labels = (const int*)d_in[1];
  float* out = (float*)d_out;

  ushort* hsK     = (ushort*)d_ws;                         // 4 MB
  ushort* hs      = (ushort*)((char*)d_ws + 4194304);      // 4 MB
  float* dbuf     = (float*)((char*)d_ws + 8388608);       // 32 KB
  float* Csp      = (float*)((char*)d_ws + 8421376);       // 800 KB
  int* cntp       = (int*)((char*)d_ws + 9240576);         // 4 KB
  float* rowpart  = (float*)((char*)d_ws + 9244672);       // 2 MB
  float* colpart  = (float*)((char*)d_ws + 11341824);      // 2 MB
  float2* rl      = (float2*)((char*)d_ws + 13438976);     // 64 KB

  norm_kernel<<<NB / 4, 256, 0, stream>>>(hidden, hs, dbuf);
  transpose_kernel<<<1024, 256, 0, stream>>>(hs, hsK);
  classsum_kernel<<<dim3(100, NSPLIT), 256, 0, stream>>>(hs, labels, Csp, cntp);
  main_kernel<<<NBLK2, 256, 0, stream>>>(hsK, rowpart, colpart);
  rowloss_kernel<<<NB / 4, 256, 0, stream>>>(hs, labels, Csp, cntp, rowpart,
                                             colpart, dbuf, rl);
  reduce_kernel<<<1, 1024, 0, stream>>>(rl, out);
}

// Round 9
// 65.341 us; speedup vs baseline: 4.3589x; 1.0159x over previous
//
#include <hip/hip_runtime.h>
#include <hip/hip_bf16.h>
#include <math.h>

typedef __attribute__((ext_vector_type(8))) short short8;
typedef __attribute__((ext_vector_type(4))) float f32x4;

#define NB 8192
#define ND 256
#define NT3 32            // 256-row tiles per side
#define NBLK3 528         // 32*33/2 triangle tiles
#define T128_USH 32768    // one 128-row K-major tile in ushorts (4096 16B units)
#define NSPLIT 8          // classsum row splits
#define LN2f 0.6931471805599453f

__device__ __forceinline__ float bf2f(ushort u) {
  unsigned int x = ((unsigned int)u) << 16;
  return __builtin_bit_cast(float, x);
}
__device__ __forceinline__ ushort f2bf(float x) {
  return __builtin_bit_cast(ushort, __float2bfloat16(x));
}

// ---- norm: normalize rows, fold 1/sqrt(T*ln2), quantize bf16, exact ||q||^2 ----
__global__ void norm_kernel(const float* __restrict__ h, ushort* __restrict__ hs,
                            float* __restrict__ dbuf) {
  const float SCALE = 1.0f / sqrtf(0.07f * 0.6931471805599453f);
  int lane = threadIdx.x & 63;
  int wave = threadIdx.x >> 6;
  int row = blockIdx.x * 4 + wave;
  const float4* rp = reinterpret_cast<const float4*>(h + (size_t)row * ND);
  float4 v = rp[lane];
  float ss = v.x * v.x + v.y * v.y + v.z * v.z + v.w * v.w;
#pragma unroll
  for (int d = 1; d <= 32; d <<= 1) ss += __shfl_xor(ss, d);
  float scale = SCALE / fmaxf(sqrtf(ss), 1e-12f);
  ushort4 o;
  o.x = f2bf(v.x * scale);
  o.y = f2bf(v.y * scale);
  o.z = f2bf(v.z * scale);
  o.w = f2bf(v.w * scale);
  reinterpret_cast<ushort4*>(hs + (size_t)row * ND)[lane] = o;
  float qx = bf2f(o.x), qy = bf2f(o.y), qz = bf2f(o.z), qw = bf2f(o.w);
  float dd = qx * qx + qy * qy + qz * qz + qw * qw;   // exact ||q||^2 (log2 units)
#pragma unroll
  for (int d = 1; d <= 32; d <<= 1) dd += __shfl_xor(dd, d);
  if (lane == 0) dbuf[row] = dd;
}

// ---- transpose: global->global 16B-unit permutation into chunked K-major ----
// unit index within 128-row tile: U = ku*128 + row  (ku 0..31, row 0..127)
__global__ void transpose_kernel(const ushort* __restrict__ hs,
                                 ushort* __restrict__ hsK) {
  int gidx = blockIdx.x * 256 + threadIdx.x;     // 262144 units total
  int tile = gidx >> 12;                         // 4096 units per 128-row tile
  int U = gidx & 4095;
  int row = U & 127;
  int ku = U >> 7;                               // 0..31
  *reinterpret_cast<short8*>(hsK + (size_t)gidx * 8) =
      *reinterpret_cast<const short8*>(
          hs + ((size_t)(tile * 128 + row) * ND) + ku * 8);
}

// ---- per-class partial sums over a 1024-row slice (list-based, coalesced) --
__global__ void classsum_kernel(const ushort* __restrict__ hs,
                                const int* __restrict__ labels,
                                float* __restrict__ Csp, int* __restrict__ cntp) {
  __shared__ int list[1024];
  __shared__ int lcnt;
  int c = blockIdx.x, sp = blockIdx.y, t = threadIdx.x;
  if (t == 0) lcnt = 0;
  __syncthreads();
  int base = sp * (NB / NSPLIT);
#pragma unroll
  for (int i = t; i < NB / NSPLIT; i += 256)
    if (labels[base + i] == c) list[atomicAdd(&lcnt, 1)] = base + i;
  __syncthreads();
  int n = lcnt;
  float acc = 0.f;
  for (int k = 0; k < n; ++k)
    acc += bf2f(hs[(size_t)list[k] * ND + t]);
  Csp[((size_t)sp * 100 + c) * ND + t] = acc;
  if (t == 0) cntp[sp * 100 + c] = n;
}

// ---- stage a 256-row x K64 slab (32KB) into LDS [ku8][row256] --------------
__device__ __forceinline__ void stage256(ushort* lds, const ushort* __restrict__ hsK,
                                         int t128a, int ch, int tid) {
#pragma unroll
  for (int i = 0; i < 4; ++i) {
    int U = i * 512 + tid;           // LDS 16B-unit index, 0..2047
    int ku = U >> 8;                 // 0..7
    int row = U & 255;               // 0..255
    int t = t128a + (row >> 7);
    const ushort* g = hsK + ((size_t)t * 4096 + (ch * 8 + ku) * 128 + (row & 127)) * 8;
    __builtin_amdgcn_global_load_lds(
        (const __attribute__((address_space(1))) unsigned int*)g,
        (__attribute__((address_space(3))) unsigned int*)(lds + (size_t)U * 8),
        16, 0, 0);
  }
}

// ---- main: 256x256 triangle tiles, 8 waves, K-streamed, exp2 in epilogue ---
__global__ __launch_bounds__(512, 1)
void main_kernel(const ushort* __restrict__ hsK,
                 float* __restrict__ rowpart, float* __restrict__ colpart) {
  __shared__ ushort Ach[2][16384];   // 2 x 32KB
  __shared__ ushort Bch[2][16384];   // 2 x 32KB
  int tid = threadIdx.x, lane = tid & 63, wave = tid >> 6;
  int g = lane >> 4, cl = lane & 15;

  int nid = (blockIdx.x & 7) * 66 + (blockIdx.x >> 3);   // 528 = 8*66, bijective
  int rb = 0, t2 = nid;
  while (t2 >= NT3 - rb) { t2 -= NT3 - rb; ++rb; }
  int cb = rb + t2;
  bool diag = (rb == cb);
  int wr = (wave >> 2) * 128;        // 0 or 128
  int wc = (wave & 3) * 64;          // 0,64,128,192

  stage256(Ach[0], hsK, rb * 2, 0, tid);
  if (!diag) stage256(Bch[0], hsK, cb * 2, 0, tid);
  __syncthreads();

  f32x4 acc[8][4];
#pragma unroll
  for (int rf = 0; rf < 8; ++rf)
#pragma unroll
    for (int cf = 0; cf < 4; ++cf) acc[rf][cf] = (f32x4){0.f, 0.f, 0.f, 0.f};

#pragma unroll
  for (int ch = 0; ch < 4; ++ch) {
    if (ch < 3) {
      stage256(Ach[(ch + 1) & 1], hsK, rb * 2, ch + 1, tid);
      if (!diag) stage256(Bch[(ch + 1) & 1], hsK, cb * 2, ch + 1, tid);
    }
    const ushort* At = Ach[ch & 1];
    const ushort* Bt = diag ? Ach[ch & 1] : Bch[ch & 1];
#pragma unroll
    for (int ks = 0; ks < 2; ++ks) {
      short8 af[8], bf[4];
#pragma unroll
      for (int rf = 0; rf < 8; ++rf)
        af[rf] = *reinterpret_cast<const short8*>(
            At + ((ks * 4 + g) * 256 + wr + rf * 16 + cl) * 8);
#pragma unroll
      for (int cf = 0; cf < 4; ++cf)
        bf[cf] = *reinterpret_cast<const short8*>(
            Bt + ((ks * 4 + g) * 256 + wc + cf * 16 + cl) * 8);
#pragma unroll
      for (int rf = 0; rf < 8; ++rf)
#pragma unroll
        for (int cf = 0; cf < 4; ++cf)
          acc[rf][cf] = __builtin_amdgcn_mfma_f32_16x16x32_bf16(af[rf], bf[cf],
                                                                acc[rf][cf], 0, 0, 0);
    }
    __syncthreads();   // drains prefetch vmcnt + protects buffers
  }

  // epilogue: e = exp2(acc); per-wave row sums (over cf,cl) and col sums (rf,q,g)
  float sr[32], cc[4];
#pragma unroll
  for (int i = 0; i < 32; ++i) sr[i] = 0.f;
#pragma unroll
  for (int i = 0; i < 4; ++i) cc[i] = 0.f;
#pragma unroll
  for (int rf = 0; rf < 8; ++rf)
#pragma unroll
    for (int cf = 0; cf < 4; ++cf)
#pragma unroll
      for (int q = 0; q < 4; ++q) {
        float e = __builtin_amdgcn_exp2f(acc[rf][cf][q]);
        sr[rf * 4 + q] += e;
        cc[cf] += e;
      }
#pragma unroll
  for (int i = 0; i < 32; ++i) {
#pragma unroll
    for (int d = 1; d <= 8; d <<= 1) sr[i] += __shfl_xor(sr[i], d);
  }
#pragma unroll
  for (int i = 0; i < 4; ++i) {
    cc[i] += __shfl_xor(cc[i], 16);
    cc[i] += __shfl_xor(cc[i], 32);
  }

  float* red = reinterpret_cast<float*>(&Ach[0][0]);  // dead after final barrier
  float* sred = red;          // [8 waves][128 rows]
  float* cred = red + 1024;   // [8 waves][64 cols]
  if (cl == 0) {
#pragma unroll
    for (int rf = 0; rf < 8; ++rf)
#pragma unroll
      for (int q = 0; q < 4; ++q)
        sred[wave * 128 + rf * 16 + g * 4 + q] = sr[rf * 4 + q];
  }
  if (g == 0) {
#pragma unroll
    for (int cf = 0; cf < 4; ++cf) cred[wave * 64 + cf * 16 + cl] = cc[cf];
  }
  __syncthreads();
  if (tid < 256) {
    int r = tid;                     // local row
    int half = r >> 7, rl2 = r & 127;
    float rv = sred[(half * 4 + 0) * 128 + rl2] + sred[(half * 4 + 1) * 128 + rl2] +
               sred[(half * 4 + 2) * 128 + rl2] + sred[(half * 4 + 3) * 128 + rl2];
    rowpart[(size_t)cb * NB + rb * 256 + r] = rv;
  } else if (!diag) {
    int c2 = tid - 256;              // local col
    int wgrp = c2 >> 6, cl2 = c2 & 63;
    float cv = cred[wgrp * 64 + cl2] + cred[(4 + wgrp) * 64 + cl2];
    colpart[(size_t)rb * NB + cb * 256 + c2] = cv;
  }
}

// ---- per-row loss ----------------------------------------------------------
__global__ void rowloss_kernel(const ushort* __restrict__ hs,
                               const int* __restrict__ labels,
                               const float* __restrict__ Csp,
                               const int* __restrict__ cntp,
                               const float* __restrict__ rowpart,
                               const float* __restrict__ colpart,
                               const float* __restrict__ dbuf,
                               float2* __restrict__ rl) {
  int lane = threadIdx.x & 63, wave = threadIdx.x >> 6;
  int row = blockIdx.x * 4 + wave;
  int lbl = labels[row];
  ushort4 qb = reinterpret_cast<const ushort4*>(hs + (size_t)row * ND)[lane];
  float4 cv = make_float4(0.f, 0.f, 0.f, 0.f);
  int ntot = 0;
#pragma unroll
  for (int sp = 0; sp < NSPLIT; ++sp) {
    float4 p = reinterpret_cast<const float4*>(
        Csp + ((size_t)sp * 100 + lbl) * ND)[lane];
    cv.x += p.x; cv.y += p.y; cv.z += p.z; cv.w += p.w;
    ntot += cntp[sp * 100 + lbl];
  }
  float dot = bf2f(qb.x) * cv.x + bf2f(qb.y) * cv.y +
              bf2f(qb.z) * cv.z + bf2f(qb.w) * cv.w;
#pragma unroll
  for (int d = 1; d <= 32; d <<= 1) dot += __shfl_xor(dot, d);

  int rb0 = row >> 8;   // this row's 256-tile index (0..31)
  float part = 0.f;
  if (lane < NT3) {
    const float* basep = (lane >= rb0) ? rowpart : colpart;
    part = basep[(size_t)lane * NB + row];
  }
#pragma unroll
  for (int d = 1; d <= 16; d <<= 1) part += __shfl_xor(part, d);

  if (lane == 0) {
    float dself = dbuf[row];
    float s = part - (1.0f - 1e-8f) * __builtin_amdgcn_exp2f(dself);
    float denom2 = log2f(s);
    float Sp2 = dot - dself;
    float n = (float)ntot - 1.0f;
    float li = 0.f, val = 0.f;
    if (n > 0.5f) { li = -LN2f * (Sp2 - n * denom2) / n; val = 1.f; }
    rl[row] = make_float2(li, val);
  }
}

__global__ __launch_bounds__(1024)
void reduce_kernel(const float2* __restrict__ rl, float* __restrict__ out) {
  int t = threadIdx.x;
  float L = 0.f, V = 0.f;
  for (int r = t; r < NB; r += 1024) { float2 p = rl[r]; L += p.x; V += p.y; }
#pragma unroll
  for (int d = 1; d <= 32; d <<= 1) { L += __shfl_xor(L, d); V += __shfl_xor(V, d); }
  __shared__ float sL[16], sV[16];
  if ((t & 63) == 0) { sL[t >> 6] = L; sV[t >> 6] = V; }
  __syncthreads();
  if (t == 0) {
    float Ls = 0.f, Vs = 0.f;
#pragma unroll
    for (int i = 0; i < 16; ++i) { Ls += sL[i]; Vs += sV[i]; }
    out[0] = Ls / fmaxf(Vs, 1.f);
  }
}

extern "C" void kernel_launch(void* const* d_in, const int* in_sizes, int n_in,
                              void* d_out, int out_size, void* d_ws, size_t ws_size,
                              hipStream_t stream) {
  const float* hidden = (const float*)d_in[0];
  const int* labels = (const int*)d_in[1];
  float* out = (float*)d_out;

  ushort* hsK     = (ushort*)d_ws;                         // 4 MB
  ushort* hs      = (ushort*)((char*)d_ws + 4194304);      // 4 MB
  float* dbuf     = (float*)((char*)d_ws + 8388608);       // 32 KB
  float* Csp      = (float*)((char*)d_ws + 8421376);       // 800 KB
  int* cntp       = (int*)((char*)d_ws + 9240576);         // 4 KB
  float* rowpart  = (float*)((char*)d_ws + 9244672);       // 1 MB (32 x 8192 x 4B)
  float* colpart  = (float*)((char*)d_ws + 10293248);      // 1 MB
  float2* rl      = (float2*)((char*)d_ws + 11341824);     // 64 KB

  norm_kernel<<<NB / 4, 256, 0, stream>>>(hidden, hs, dbuf);
  transpose_kernel<<<1024, 256, 0, stream>>>(hs, hsK);
  classsum_kernel<<<dim3(100, NSPLIT), 256, 0, stream>>>(hs, labels, Csp, cntp);
  main_kernel<<<NBLK3, 512, 0, stream>>>(hsK, rowpart, colpart);
  rowloss_kernel<<<NB / 4, 256, 0, stream>>>(hs, labels, Csp, cntp, rowpart,
                                             colpart, dbuf, rl);
  reduce_kernel<<<1, 1024, 0, stream>>>(rl, out);
}